// Round 1
// baseline (593.102 us; speedup 1.0000x reference)
//
#include <hip/hip_runtime.h>
#include <hip/hip_bf16.h>
#include <math.h>

#define NN 100000
#define NE 3200000
#define NF 512
#define NTILE 6250   // NN/16 exactly
#define NB 782       // ceil(NN/128) dst-buckets of 128 nodes
#define NCH 256      // edge chunks
#define CHUNK 12500  // NE/NCH exactly
#define HSZ (NB * NCH)  // 200192
#define NSB1 ((HSZ + 1023) / 1024)  // 196

typedef __attribute__((ext_vector_type(8))) short short8;
typedef __attribute__((ext_vector_type(4))) float f32x4;

__device__ inline unsigned bf16_rne(float f) {
    unsigned u = __builtin_bit_cast(unsigned, f);
    return (u + 0x7FFFu + ((u >> 16) & 1u)) >> 16;
}
__device__ inline float bf16_back(unsigned h) {
    return __builtin_bit_cast(float, h << 16);
}

// ---------------- t=0 ----------------
__global__ void k_initt(float* __restrict__ tbuf) {
    if (threadIdx.x < 16) tbuf[threadIdx.x] = 0.0f;
}

// ---------------- per-chunk bucket histogram (LDS, no global atomics) ---------
__global__ __launch_bounds__(256) void k_hist(const int* __restrict__ dst,
                                              int* __restrict__ hist) {
    __shared__ int lcnt[NB];
    for (int i = threadIdx.x; i < NB; i += 256) lcnt[i] = 0;
    __syncthreads();
    const int e0 = blockIdx.x * CHUNK;
    for (int i = threadIdx.x; i < CHUNK; i += 256)
        atomicAdd(&lcnt[dst[e0 + i] >> 7], 1);
    __syncthreads();
    for (int b = threadIdx.x; b < NB; b += 256)
        hist[b * NCH + blockIdx.x] = lcnt[b];
}

// ---------------- 3-kernel exclusive scan of hist (in place) ----------------
__global__ __launch_bounds__(1024) void k_scan1(int* __restrict__ hist,
                                                int* __restrict__ bsum) {
    __shared__ int tmp[2][1024];
    int tid = threadIdx.x;
    int i = blockIdx.x * 1024 + tid;
    int v = (i < HSZ) ? hist[i] : 0;
    int pp = 0;
    tmp[0][tid] = v;
    __syncthreads();
    for (int off = 1; off < 1024; off <<= 1) {
        int t = tmp[pp][tid];
        if (tid >= off) t += tmp[pp][tid - off];
        tmp[1 - pp][tid] = t;
        __syncthreads();
        pp = 1 - pp;
    }
    int incl = tmp[pp][tid];
    if (i < HSZ) hist[i] = incl - v;  // exclusive, sans block offset
    if (tid == 1023) bsum[blockIdx.x] = incl;
}

__global__ __launch_bounds__(256) void k_scan2(int* __restrict__ bsum) {
    __shared__ int tmp[2][256];
    int tid = threadIdx.x;
    int v = (tid < NSB1) ? bsum[tid] : 0;
    int pp = 0;
    tmp[0][tid] = v;
    __syncthreads();
    for (int off = 1; off < 256; off <<= 1) {
        int t = tmp[pp][tid];
        if (tid >= off) t += tmp[pp][tid - off];
        tmp[1 - pp][tid] = t;
        __syncthreads();
        pp = 1 - pp;
    }
    if (tid < NSB1) bsum[tid] = tmp[pp][tid] - v;  // exclusive
}

__global__ __launch_bounds__(256) void k_scan3(int* __restrict__ hist,
                                               const int* __restrict__ bsum,
                                               float* __restrict__ cacc) {
    int i = blockIdx.x * 256 + threadIdx.x;
    if (i < HSZ) hist[i] += bsum[i >> 10];
    if (i == 0) hist[HSZ] = NE;
    if (i < NN) cacc[i] = 0.0f;  // zero column-sum accumulator for k_gather
}

// ---------------- placement: LDS cursors, zero global atomics ----------------
__global__ __launch_bounds__(256) void k_place2(const int* __restrict__ src,
                                                const int* __restrict__ dst,
                                                const int* __restrict__ hist,
                                                unsigned* __restrict__ packed) {
    __shared__ int sbase[NB];
    __shared__ int lcur[NB];
    const int c = blockIdx.x;
    for (int b = threadIdx.x; b < NB; b += 256) {
        sbase[b] = hist[b * NCH + c];
        lcur[b] = 0;
    }
    __syncthreads();
    const int e0 = c * CHUNK;
    for (int i = threadIdx.x; i < CHUNK; i += 256) {
        int d = dst[e0 + i];
        int s = src[e0 + i];
        int b = d >> 7;
        int pos = atomicAdd(&lcur[b], 1);
        packed[sbase[b] + pos] = ((unsigned)(d & 127) << 17) | (unsigned)s;
    }
}

// ---------------- per-bucket counting sort -> node CSR (+dinv), in place ------
#define BCAP 8192  // 64 sigma above mean bucket size 4093
__global__ __launch_bounds__(256) void k_bsort(unsigned* __restrict__ packed,
                                               const int* __restrict__ hist,
                                               int* __restrict__ row_start,
                                               float* __restrict__ dinv) {
    __shared__ unsigned stage[BCAP];
    __shared__ int cnt[128];
    __shared__ int t0[128], t1[128];
    const int tid = threadIdx.x;
    const int b = blockIdx.x;
    const int beg = hist[b * NCH], end = hist[(b + 1) * NCH];
    const int sz = end - beg;
    if (tid < 128) cnt[tid] = 0;
    __syncthreads();
    for (int i = tid; i < sz; i += 256) {
        unsigned p = packed[beg + i];
        if (i < BCAP) stage[i] = p;
        atomicAdd(&cnt[p >> 17], 1);
    }
    __syncthreads();
    // inclusive Hillis-Steele scan over 128 counts
    if (tid < 128) t0[tid] = cnt[tid];
    __syncthreads();
    int pp = 0;
    for (int off = 1; off < 128; off <<= 1) {
        if (tid < 128) {
            int t = (pp ? t1[tid] : t0[tid]);
            if (tid >= off) t += (pp ? t1[tid - off] : t0[tid - off]);
            if (pp) t0[tid] = t; else t1[tid] = t;
        }
        __syncthreads();
        pp = 1 - pp;
    }
    if (tid < 128) {
        int incl = pp ? t1[tid] : t0[tid];
        int excl = incl - cnt[tid];
        int n = b * 128 + tid;
        if (n < NN) {
            row_start[n] = beg + excl;
            dinv[n] = rsqrtf((float)cnt[tid] + 1.0f);
        }
        cnt[tid] = excl;  // reuse as cursor
    }
    __syncthreads();
    for (int i = tid; i < sz; i += 256) {
        unsigned p = (i < BCAP) ? stage[i] : packed[beg + i];
        int k = p >> 17;
        int pos = atomicAdd(&cnt[k], 1);
        packed[beg + pos] = p & 0x1FFFFu;
    }
    if (b == NB - 1 && tid == 0) row_start[NN] = NE;
}

// ---------------- GEMM1 via MFMA 16x16x32 bf16, split hi/lo ----------------
// Writes hs[n][c] = dinv[n] * (x@W1)[n][c]
__global__ __launch_bounds__(256) void k_gemm1(
    const float* __restrict__ x, const float* __restrict__ W1,
    const float* __restrict__ dinv, float* __restrict__ hs) {
    __shared__ short8 Bh[1024];  // idx = (kk*4+q)*16 + c
    __shared__ short8 Bl[1024];

    const int t = threadIdx.x;
    {   // stage W: thread (c,q,kk0) handles kk = kk0*4+i
        const int c = t & 15, q = (t >> 4) & 3, kk0 = t >> 6;
        for (int i = 0; i < 4; ++i) {
            const int kk = kk0 * 4 + i;
            short8 hi, lo;
#pragma unroll
            for (int j = 0; j < 8; ++j) {
                float w = W1[(kk * 32 + q * 8 + j) * 16 + c];
                unsigned h = bf16_rne(w);
                float back = bf16_back(h);
                unsigned l = bf16_rne(w - back);
                hi[j] = (short)h;
                lo[j] = (short)l;
            }
            Bh[(kk * 4 + q) * 16 + c] = hi;
            Bl[(kk * 4 + q) * 16 + c] = lo;
        }
    }
    __syncthreads();

    const int lane = t & 63;
    const int wave = blockIdx.x * 4 + (t >> 6);
    if (wave >= NTILE) return;
    const int nb = wave * 16;
    const int m = lane & 15;  // A row within tile AND B/C col (channel)
    const int q = lane >> 4;

    const float4* xrow = (const float4*)(x + (size_t)(nb + m) * NF + q * 8);
    float4 xr[32];
#pragma unroll
    for (int kk = 0; kk < 16; ++kk) {
        xr[2 * kk] = xrow[kk * 8];
        xr[2 * kk + 1] = xrow[kk * 8 + 1];
    }

    f32x4 acc = {0.f, 0.f, 0.f, 0.f};
#pragma unroll
    for (int kk = 0; kk < 16; ++kk) {
        float f[8] = {xr[2 * kk].x,     xr[2 * kk].y,     xr[2 * kk].z,
                      xr[2 * kk].w,     xr[2 * kk + 1].x, xr[2 * kk + 1].y,
                      xr[2 * kk + 1].z, xr[2 * kk + 1].w};
        short8 ah, al;
#pragma unroll
        for (int j = 0; j < 8; ++j) {
            unsigned h = bf16_rne(f[j]);
            ah[j] = (short)h;
            al[j] = (short)bf16_rne(f[j] - bf16_back(h));
        }
        short8 bh = Bh[(kk * 4 + q) * 16 + m];
        short8 bl = Bl[(kk * 4 + q) * 16 + m];
        acc = __builtin_amdgcn_mfma_f32_16x16x32_bf16(ah, bh, acc, 0, 0, 0);
        acc = __builtin_amdgcn_mfma_f32_16x16x32_bf16(ah, bl, acc, 0, 0, 0);
        acc = __builtin_amdgcn_mfma_f32_16x16x32_bf16(al, bh, acc, 0, 0, 0);
    }

    // C/D: col=lane&15, row=q*4+reg
#pragma unroll
    for (int r = 0; r < 4; ++r) {
        const int n = nb + q * 4 + r;
        hs[n * 16 + m] = dinv[n] * acc[r];
    }
}

// ---------------- gather: out[n] = dinv[n]*(hs[n] + sum_{s in N(n)} hs[s]) ------
// one wave per node; lanes = (edge subgroup g=lane>>4) x (channel c=lane&15)
// fused: cacc[s] += dinv[n] per edge (s,n)  -> column sums of A-hat for layer 2
__global__ __launch_bounds__(256) void k_gather(
    const float* __restrict__ hs, const float* __restrict__ dinv,
    const int* __restrict__ row_start, const int* __restrict__ csr,
    float* __restrict__ out, float* __restrict__ cacc) {
    const int lane = threadIdx.x & 63;
    const int n = blockIdx.x * 4 + (threadIdx.x >> 6);
    const int c = lane & 15;
    const int g = lane >> 4;
    const bool lead = (c == 0);
    const float dn = dinv[n];
    const int beg = row_start[n], end = row_start[n + 1];
    float acc = 0.0f;
    int i = beg + g;
    for (; i + 4 < end; i += 8) {  // 2 edges per group per iter (MLP)
        int s0 = csr[i];
        int s1 = csr[i + 4];
        acc += hs[s0 * 16 + c];
        acc += hs[s1 * 16 + c];
        if (lead) {
            atomicAdd(&cacc[s0], dn);
            atomicAdd(&cacc[s1], dn);
        }
    }
    if (i < end) {
        int s0 = csr[i];
        acc += hs[s0 * 16 + c];
        if (lead) atomicAdd(&cacc[s0], dn);
    }
    acc += __shfl_xor(acc, 16, 64);
    acc += __shfl_xor(acc, 32, 64);
    if (lane < 16) out[n * 16 + c] = dn * (acc + hs[n * 16 + c]);
}

// ---------------- weighted channel reduce -------------------------------------
// t[c] = sum_n dinv[n]*(cacc[n]+dinv[n]) * relu(a1[n][c] + b1[c])
// (mean-pooling commutes with the layer-2 scatter: sum_d Ahat[d,s] = dinv[s]*(c[s]+dinv[s]))
__global__ void k_wreduce(const float* __restrict__ a1, const float* __restrict__ dinv,
                          const float* __restrict__ cacc, const float* __restrict__ b1,
                          float* __restrict__ tbuf) {
    int t = blockIdx.x * blockDim.x + threadIdx.x;
    int c = t & 15;
    int n0 = t >> 4;
    int nstride = (gridDim.x * blockDim.x) >> 4;
    float b1c = b1[c];
    float s = 0.0f;
    for (int n = n0; n < NN; n += nstride) {
        float dn = dinv[n];
        float w = dn * (cacc[n] + dn);
        float a = a1[n * 16 + c];
        s += w * fmaxf(a + b1c, 0.0f);
    }
    s += __shfl_xor(s, 16, 64);
    s += __shfl_xor(s, 32, 64);
    __shared__ float red[4][16];
    int wid = threadIdx.x >> 6;
    int lane = threadIdx.x & 63;
    if (lane < 16) red[wid][lane] = s;
    __syncthreads();
    if (threadIdx.x < 16) {
        float tot = red[0][threadIdx.x] + red[1][threadIdx.x] + red[2][threadIdx.x] +
                    red[3][threadIdx.x];
        atomicAdd(&tbuf[threadIdx.x], tot);
    }
}

// ---------------- finalize: pooled = (t @ W2)/N + b2, then softmax ------------
__global__ void k_softmax(const float* __restrict__ tbuf, const float* __restrict__ W2,
                          const float* __restrict__ b2, float* __restrict__ out) {
    __shared__ float tv[16];
    __shared__ float vals[16];
    int k = threadIdx.x;
    if (k < 16) tv[k] = tbuf[k];
    __syncthreads();
    if (k < 16) {
        float acc = 0.0f;
        for (int c = 0; c < 16; ++c) acc += tv[c] * W2[c * 16 + k];
        vals[k] = acc * (1.0f / NN) + b2[k];
    }
    __syncthreads();
    if (k < 16) {
        float m = -INFINITY;
        for (int i = 0; i < 16; ++i) m = fmaxf(m, vals[i]);
        float sum = 0.0f;
        for (int i = 0; i < 16; ++i) sum += expf(vals[i] - m);
        out[k] = expf(vals[k] - m) / sum;
    }
}

extern "C" void kernel_launch(void* const* d_in, const int* in_sizes, int n_in,
                              void* d_out, int out_size, void* d_ws, size_t ws_size,
                              hipStream_t stream) {
    const float* x = (const float*)d_in[0];
    const int* edge = (const int*)d_in[1];
    const float* W1 = (const float*)d_in[2];
    const float* b1 = (const float*)d_in[3];
    const float* W2 = (const float*)d_in[4];
    const float* b2 = (const float*)d_in[5];
    const int* src = edge;
    const int* dst = edge + NE;

    char* ws = (char*)d_ws;
    int* hist = (int*)ws;                          // HSZ+1
    int* bsum = hist + HSZ + 1;                    // 256
    unsigned* packed = (unsigned*)(bsum + 256);    // NE (becomes csr)
    int* row_start = (int*)(packed + NE);          // NN+1
    float* dinv = (float*)(row_start + NN + 1);    // NN
    float* hs = dinv + NN;                         // NN*16
    float* abuf = hs + (size_t)NN * 16;            // NN*16
    float* cacc = abuf + (size_t)NN * 16;          // NN
    float* tbuf = cacc + NN;                       // 16

    float* out = (float*)d_out;
    const int* csr = (const int*)packed;

    k_initt<<<1, 64, 0, stream>>>(tbuf);
    k_hist<<<NCH, 256, 0, stream>>>(dst, hist);
    k_scan1<<<NSB1, 1024, 0, stream>>>(hist, bsum);
    k_scan2<<<1, 256, 0, stream>>>(bsum);
    k_scan3<<<(HSZ + 255) / 256, 256, 0, stream>>>(hist, bsum, cacc);
    k_place2<<<NCH, 256, 0, stream>>>(src, dst, hist, packed);
    k_bsort<<<NB, 256, 0, stream>>>(packed, hist, row_start, dinv);

    k_gemm1<<<(NTILE + 3) / 4, 256, 0, stream>>>(x, W1, dinv, hs);
    k_gather<<<NN / 4, 256, 0, stream>>>(hs, dinv, row_start, csr, abuf, cacc);
    k_wreduce<<<256, 256, 0, stream>>>(abuf, dinv, cacc, b1, tbuf);
    k_softmax<<<1, 64, 0, stream>>>(tbuf, W2, b2, out);
}

// Round 2
// 534.879 us; speedup vs baseline: 1.1089x; 1.1089x over previous
//
#include <hip/hip_runtime.h>
#include <hip/hip_bf16.h>
#include <math.h>

#define NN 100000
#define NE 3200000
#define NF 512
#define NTILE 6250   // NN/16 exactly
#define NB 782       // ceil(NN/128) buckets of 128 nodes
#define NCH 256      // edge chunks
#define CHUNK 12500  // NE/NCH exactly
#define HSZ (NB * NCH)   // 200192 (dst hist)
#define HSZ2 (2 * HSZ)   // 400384 (dst hist + src hist)
#define NSB1 ((HSZ2 + 1023) / 1024)  // 391

typedef __attribute__((ext_vector_type(8))) short short8;
typedef __attribute__((ext_vector_type(4))) float f32x4;

__device__ inline unsigned bf16_rne(float f) {
    unsigned u = __builtin_bit_cast(unsigned, f);
    return (u + 0x7FFFu + ((u >> 16) & 1u)) >> 16;
}
__device__ inline float bf16_back(unsigned h) {
    return __builtin_bit_cast(float, h << 16);
}

// ---------------- t=0 ----------------
__global__ void k_initt(float* __restrict__ tbuf) {
    if (threadIdx.x < 16) tbuf[threadIdx.x] = 0.0f;
}

// -------- per-chunk bucket histogram for BOTH keys (LDS, no global atomics) ----
// hist[0..HSZ)        : dst-keyed counts
// hist[HSZ..2*HSZ)    : src-keyed counts
__global__ __launch_bounds__(256) void k_hist(const int* __restrict__ src,
                                              const int* __restrict__ dst,
                                              int* __restrict__ hist) {
    __shared__ int lcntD[NB];
    __shared__ int lcntS[NB];
    for (int i = threadIdx.x; i < NB; i += 256) { lcntD[i] = 0; lcntS[i] = 0; }
    __syncthreads();
    const int e0 = blockIdx.x * CHUNK;
    for (int i = threadIdx.x; i < CHUNK; i += 256) {
        atomicAdd(&lcntD[dst[e0 + i] >> 7], 1);
        atomicAdd(&lcntS[src[e0 + i] >> 7], 1);
    }
    __syncthreads();
    for (int b = threadIdx.x; b < NB; b += 256) {
        hist[b * NCH + blockIdx.x] = lcntD[b];
        hist[HSZ + b * NCH + blockIdx.x] = lcntS[b];
    }
}

// ---------------- 3-kernel exclusive scan of hist[0..HSZ2) (in place) ---------
// Joint scan: src-region offsets automatically start at NE (total of dst counts),
// which is exactly where the src-copy lives in the shared `packed` buffer.
__global__ __launch_bounds__(1024) void k_scan1(int* __restrict__ hist,
                                                int* __restrict__ bsum) {
    __shared__ int tmp[2][1024];
    int tid = threadIdx.x;
    int i = blockIdx.x * 1024 + tid;
    int v = (i < HSZ2) ? hist[i] : 0;
    int pp = 0;
    tmp[0][tid] = v;
    __syncthreads();
    for (int off = 1; off < 1024; off <<= 1) {
        int t = tmp[pp][tid];
        if (tid >= off) t += tmp[pp][tid - off];
        tmp[1 - pp][tid] = t;
        __syncthreads();
        pp = 1 - pp;
    }
    int incl = tmp[pp][tid];
    if (i < HSZ2) hist[i] = incl - v;  // exclusive, sans block offset
    if (tid == 1023) bsum[blockIdx.x] = incl;
}

__global__ __launch_bounds__(512) void k_scan2(int* __restrict__ bsum) {
    __shared__ int tmp[2][512];
    int tid = threadIdx.x;
    int v = (tid < NSB1) ? bsum[tid] : 0;
    int pp = 0;
    tmp[0][tid] = v;
    __syncthreads();
    for (int off = 1; off < 512; off <<= 1) {
        int t = tmp[pp][tid];
        if (tid >= off) t += tmp[pp][tid - off];
        tmp[1 - pp][tid] = t;
        __syncthreads();
        pp = 1 - pp;
    }
    if (tid < NSB1) bsum[tid] = tmp[pp][tid] - v;  // exclusive
}

__global__ __launch_bounds__(256) void k_scan3(int* __restrict__ hist,
                                               const int* __restrict__ bsum) {
    int i = blockIdx.x * 256 + threadIdx.x;
    if (i < HSZ2) hist[i] += bsum[i >> 10];
    if (i == 0) hist[HSZ2] = 2 * NE;  // end sentinel for last src bucket
    // note: hist[HSZ] == NE automatically (scan total of dst region)
}

// -------- placement of BOTH copies: LDS cursors, zero global atomics ----------
// packed[0..NE)      : dst-bucketed, payload = ((dst&127)<<17) | src
// packed[NE..2*NE)   : src-bucketed, payload = ((src&127)<<17) | dst
__global__ __launch_bounds__(256) void k_place2(const int* __restrict__ src,
                                                const int* __restrict__ dst,
                                                const int* __restrict__ hist,
                                                unsigned* __restrict__ packed) {
    __shared__ int sbD[NB];
    __shared__ int lcD[NB];
    __shared__ int sbS[NB];
    __shared__ int lcS[NB];
    const int c = blockIdx.x;
    for (int b = threadIdx.x; b < NB; b += 256) {
        sbD[b] = hist[b * NCH + c];
        lcD[b] = 0;
        sbS[b] = hist[HSZ + b * NCH + c];
        lcS[b] = 0;
    }
    __syncthreads();
    const int e0 = c * CHUNK;
    for (int i = threadIdx.x; i < CHUNK; i += 256) {
        int d = dst[e0 + i];
        int s = src[e0 + i];
        int bd = d >> 7;
        int pd = atomicAdd(&lcD[bd], 1);
        packed[sbD[bd] + pd] = ((unsigned)(d & 127) << 17) | (unsigned)s;
        int bs = s >> 7;
        int ps = atomicAdd(&lcS[bs], 1);
        packed[sbS[bs] + ps] = ((unsigned)(s & 127) << 17) | (unsigned)d;
    }
}

// ---------------- per-bucket counting sort -> node CSR (+dinv), in place ------
#define BCAP 8192  // 64 sigma above mean bucket size 4093
__global__ __launch_bounds__(256) void k_bsort(unsigned* __restrict__ packed,
                                               const int* __restrict__ hist,
                                               int* __restrict__ row_start,
                                               float* __restrict__ dinv) {
    __shared__ unsigned stage[BCAP];
    __shared__ int cnt[128];
    __shared__ int t0[128], t1[128];
    const int tid = threadIdx.x;
    const int b = blockIdx.x;
    const int beg = hist[b * NCH], end = hist[(b + 1) * NCH];
    const int sz = end - beg;
    if (tid < 128) cnt[tid] = 0;
    __syncthreads();
    for (int i = tid; i < sz; i += 256) {
        unsigned p = packed[beg + i];
        if (i < BCAP) stage[i] = p;
        atomicAdd(&cnt[p >> 17], 1);
    }
    __syncthreads();
    // inclusive Hillis-Steele scan over 128 counts
    if (tid < 128) t0[tid] = cnt[tid];
    __syncthreads();
    int pp = 0;
    for (int off = 1; off < 128; off <<= 1) {
        if (tid < 128) {
            int t = (pp ? t1[tid] : t0[tid]);
            if (tid >= off) t += (pp ? t1[tid - off] : t0[tid - off]);
            if (pp) t0[tid] = t; else t1[tid] = t;
        }
        __syncthreads();
        pp = 1 - pp;
    }
    if (tid < 128) {
        int incl = pp ? t1[tid] : t0[tid];
        int excl = incl - cnt[tid];
        int n = b * 128 + tid;
        if (n < NN) {
            row_start[n] = beg + excl;
            dinv[n] = rsqrtf((float)cnt[tid] + 1.0f);
        }
        cnt[tid] = excl;  // reuse as cursor
    }
    __syncthreads();
    for (int i = tid; i < sz; i += 256) {
        unsigned p = (i < BCAP) ? stage[i] : packed[beg + i];
        int k = p >> 17;
        int pos = atomicAdd(&cnt[k], 1);
        packed[beg + pos] = p & 0x1FFFFu;
    }
    if (b == NB - 1 && tid == 0) row_start[NN] = NE;
}

// -------- column sums of A-hat: cacc[s] = sum_{edges s->d} dinv[d] ------------
// per src-bucket LDS accumulation over the src-bucketed copy; no sort needed.
__global__ __launch_bounds__(256) void k_csum(const unsigned* __restrict__ packed,
                                              const int* __restrict__ hist,
                                              const float* __restrict__ dinv,
                                              float* __restrict__ cacc) {
    __shared__ float sums[128];
    const int tid = threadIdx.x;
    const int b = blockIdx.x;
    if (tid < 128) sums[tid] = 0.0f;
    __syncthreads();
    const int beg = hist[HSZ + b * NCH], end = hist[HSZ + (b + 1) * NCH];
    const int sz = end - beg;
    for (int i = tid; i < sz; i += 256) {
        unsigned p = packed[beg + i];
        atomicAdd(&sums[p >> 17], dinv[p & 0x1FFFFu]);
    }
    __syncthreads();
    const int n = b * 128 + tid;
    if (tid < 128 && n < NN) cacc[n] = sums[tid];
}

// ---------------- GEMM1 via MFMA 16x16x32 bf16, split hi/lo ----------------
// Writes hs[n][c] = dinv[n] * (x@W1)[n][c]
__global__ __launch_bounds__(256) void k_gemm1(
    const float* __restrict__ x, const float* __restrict__ W1,
    const float* __restrict__ dinv, float* __restrict__ hs) {
    __shared__ short8 Bh[1024];  // idx = (kk*4+q)*16 + c
    __shared__ short8 Bl[1024];

    const int t = threadIdx.x;
    {   // stage W: thread (c,q,kk0) handles kk = kk0*4+i
        const int c = t & 15, q = (t >> 4) & 3, kk0 = t >> 6;
        for (int i = 0; i < 4; ++i) {
            const int kk = kk0 * 4 + i;
            short8 hi, lo;
#pragma unroll
            for (int j = 0; j < 8; ++j) {
                float w = W1[(kk * 32 + q * 8 + j) * 16 + c];
                unsigned h = bf16_rne(w);
                float back = bf16_back(h);
                unsigned l = bf16_rne(w - back);
                hi[j] = (short)h;
                lo[j] = (short)l;
            }
            Bh[(kk * 4 + q) * 16 + c] = hi;
            Bl[(kk * 4 + q) * 16 + c] = lo;
        }
    }
    __syncthreads();

    const int lane = t & 63;
    const int wave = blockIdx.x * 4 + (t >> 6);
    if (wave >= NTILE) return;
    const int nb = wave * 16;
    const int m = lane & 15;  // A row within tile AND B/C col (channel)
    const int q = lane >> 4;

    const float4* xrow = (const float4*)(x + (size_t)(nb + m) * NF + q * 8);
    float4 xr[32];
#pragma unroll
    for (int kk = 0; kk < 16; ++kk) {
        xr[2 * kk] = xrow[kk * 8];
        xr[2 * kk + 1] = xrow[kk * 8 + 1];
    }

    f32x4 acc = {0.f, 0.f, 0.f, 0.f};
#pragma unroll
    for (int kk = 0; kk < 16; ++kk) {
        float f[8] = {xr[2 * kk].x,     xr[2 * kk].y,     xr[2 * kk].z,
                      xr[2 * kk].w,     xr[2 * kk + 1].x, xr[2 * kk + 1].y,
                      xr[2 * kk + 1].z, xr[2 * kk + 1].w};
        short8 ah, al;
#pragma unroll
        for (int j = 0; j < 8; ++j) {
            unsigned h = bf16_rne(f[j]);
            ah[j] = (short)h;
            al[j] = (short)bf16_rne(f[j] - bf16_back(h));
        }
        short8 bh = Bh[(kk * 4 + q) * 16 + m];
        short8 bl = Bl[(kk * 4 + q) * 16 + m];
        acc = __builtin_amdgcn_mfma_f32_16x16x32_bf16(ah, bh, acc, 0, 0, 0);
        acc = __builtin_amdgcn_mfma_f32_16x16x32_bf16(ah, bl, acc, 0, 0, 0);
        acc = __builtin_amdgcn_mfma_f32_16x16x32_bf16(al, bh, acc, 0, 0, 0);
    }

    // C/D: col=lane&15, row=q*4+reg
#pragma unroll
    for (int r = 0; r < 4; ++r) {
        const int n = nb + q * 4 + r;
        hs[n * 16 + m] = dinv[n] * acc[r];
    }
}

// ---------------- gather: out[n] = dinv[n]*(hs[n] + sum_{s in N(n)} hs[s]) ----
// one wave per node; lane = (edge-slot e=lane>>2) x (channel quad q=lane&3)
// each lane loads a float4 (quarter row); 16 edge rows in flight per wave,
// x2 with unroll -> 32 independent 64B loads per wave for MLP.
__global__ __launch_bounds__(256) void k_gather(
    const float* __restrict__ hs, const float* __restrict__ dinv,
    const int* __restrict__ row_start, const int* __restrict__ csr,
    float* __restrict__ out) {
    const int lane = threadIdx.x & 63;
    const int n = blockIdx.x * 4 + (threadIdx.x >> 6);
    const int e = lane >> 2;  // edge slot 0..15
    const int q = lane & 3;   // channel quad 0..3
    const int beg = row_start[n], end = row_start[n + 1];
    float a0 = 0.f, a1 = 0.f, a2 = 0.f, a3 = 0.f;
    int i = beg + e;
    for (; i + 16 < end; i += 32) {
        int s0 = csr[i];
        int s1 = csr[i + 16];
        const float4 v0 = *(const float4*)(hs + s0 * 16 + q * 4);
        const float4 v1 = *(const float4*)(hs + s1 * 16 + q * 4);
        a0 += v0.x + v1.x;
        a1 += v0.y + v1.y;
        a2 += v0.z + v1.z;
        a3 += v0.w + v1.w;
    }
    if (i < end) {
        const float4 v = *(const float4*)(hs + csr[i] * 16 + q * 4);
        a0 += v.x; a1 += v.y; a2 += v.z; a3 += v.w;
    }
    // reduce across the 16 edge slots (lane bits 2..5)
    for (int m = 4; m < 64; m <<= 1) {
        a0 += __shfl_xor(a0, m, 64);
        a1 += __shfl_xor(a1, m, 64);
        a2 += __shfl_xor(a2, m, 64);
        a3 += __shfl_xor(a3, m, 64);
    }
    if (lane < 4) {  // lane == q here; holds totals for channels 4q..4q+3
        const float dn = dinv[n];
        const float4 hv = *(const float4*)(hs + n * 16 + lane * 4);
        float4 r;
        r.x = dn * (a0 + hv.x);
        r.y = dn * (a1 + hv.y);
        r.z = dn * (a2 + hv.z);
        r.w = dn * (a3 + hv.w);
        *(float4*)(out + n * 16 + lane * 4) = r;
    }
}

// ---------------- weighted channel reduce -------------------------------------
// t[c] = sum_n dinv[n]*(cacc[n]+dinv[n]) * relu(a1[n][c] + b1[c])
// (mean-pooling commutes with the layer-2 scatter: sum_d Ahat[d,s] = dinv[s]*(c[s]+dinv[s]))
__global__ void k_wreduce(const float* __restrict__ a1, const float* __restrict__ dinv,
                          const float* __restrict__ cacc, const float* __restrict__ b1,
                          float* __restrict__ tbuf) {
    int t = blockIdx.x * blockDim.x + threadIdx.x;
    int c = t & 15;
    int n0 = t >> 4;
    int nstride = (gridDim.x * blockDim.x) >> 4;
    float b1c = b1[c];
    float s = 0.0f;
    for (int n = n0; n < NN; n += nstride) {
        float dn = dinv[n];
        float w = dn * (cacc[n] + dn);
        float a = a1[n * 16 + c];
        s += w * fmaxf(a + b1c, 0.0f);
    }
    s += __shfl_xor(s, 16, 64);
    s += __shfl_xor(s, 32, 64);
    __shared__ float red[4][16];
    int wid = threadIdx.x >> 6;
    int lane = threadIdx.x & 63;
    if (lane < 16) red[wid][lane] = s;
    __syncthreads();
    if (threadIdx.x < 16) {
        float tot = red[0][threadIdx.x] + red[1][threadIdx.x] + red[2][threadIdx.x] +
                    red[3][threadIdx.x];
        atomicAdd(&tbuf[threadIdx.x], tot);
    }
}

// ---------------- finalize: pooled = (t @ W2)/N + b2, then softmax ------------
__global__ void k_softmax(const float* __restrict__ tbuf, const float* __restrict__ W2,
                          const float* __restrict__ b2, float* __restrict__ out) {
    __shared__ float tv[16];
    __shared__ float vals[16];
    int k = threadIdx.x;
    if (k < 16) tv[k] = tbuf[k];
    __syncthreads();
    if (k < 16) {
        float acc = 0.0f;
        for (int c = 0; c < 16; ++c) acc += tv[c] * W2[c * 16 + k];
        vals[k] = acc * (1.0f / NN) + b2[k];
    }
    __syncthreads();
    if (k < 16) {
        float m = -INFINITY;
        for (int i = 0; i < 16; ++i) m = fmaxf(m, vals[i]);
        float sum = 0.0f;
        for (int i = 0; i < 16; ++i) sum += expf(vals[i] - m);
        out[k] = expf(vals[k] - m) / sum;
    }
}

extern "C" void kernel_launch(void* const* d_in, const int* in_sizes, int n_in,
                              void* d_out, int out_size, void* d_ws, size_t ws_size,
                              hipStream_t stream) {
    const float* x = (const float*)d_in[0];
    const int* edge = (const int*)d_in[1];
    const float* W1 = (const float*)d_in[2];
    const float* b1 = (const float*)d_in[3];
    const float* W2 = (const float*)d_in[4];
    const float* b2 = (const float*)d_in[5];
    const int* src = edge;
    const int* dst = edge + NE;

    // layout padded so hs/abuf are 16B aligned
    char* ws = (char*)d_ws;
    int* hist = (int*)ws;                             // HSZ2+1 (pad to 400388)
    int* bsum = hist + 400388;                        // 512
    unsigned* packed = (unsigned*)(bsum + 512);       // 2*NE (first NE becomes csr)
    int* row_start = (int*)(packed + 2 * NE);         // NN+1 (pad to 100004)
    float* dinv = (float*)(row_start + 100004);       // NN
    float* hs = dinv + NN;                            // NN*16 (16B aligned)
    float* abuf = hs + (size_t)NN * 16;               // NN*16
    float* cacc = abuf + (size_t)NN * 16;             // NN
    float* tbuf = cacc + NN;                          // 16

    float* out = (float*)d_out;
    const int* csr = (const int*)packed;

    k_initt<<<1, 64, 0, stream>>>(tbuf);
    k_hist<<<NCH, 256, 0, stream>>>(src, dst, hist);
    k_scan1<<<NSB1, 1024, 0, stream>>>(hist, bsum);
    k_scan2<<<1, 512, 0, stream>>>(bsum);
    k_scan3<<<HSZ2 / 256, 256, 0, stream>>>(hist, bsum);
    k_place2<<<NCH, 256, 0, stream>>>(src, dst, hist, packed);
    k_bsort<<<NB, 256, 0, stream>>>(packed, hist, row_start, dinv);
    k_csum<<<NB, 256, 0, stream>>>(packed, hist, dinv, cacc);

    k_gemm1<<<(NTILE + 3) / 4, 256, 0, stream>>>(x, W1, dinv, hs);
    k_gather<<<NN / 4, 256, 0, stream>>>(hs, dinv, row_start, csr, abuf);
    k_wreduce<<<256, 256, 0, stream>>>(abuf, dinv, cacc, b1, tbuf);
    k_softmax<<<1, 64, 0, stream>>>(tbuf, W2, b2, out);
}